// Round 4
// baseline (225.180 us; speedup 1.0000x reference)
//
#include <hip/hip_runtime.h>

#define D       32
#define BS      256
#define CBLK    1000         // edge-chunk blocks for the local-sort pass
#define BSH     7            // bucket shift: 128 nodes per bucket
#define BNODES  128
#define MAXBUCK 1024         // LDS histogram capacity (NBUCK = ceil(N/128) must fit)
#define SBUF_CAP 1792        // LDS staging capacity in pass 1 (EPB must fit)
#define ECAP    4096         // LDS edge-buffer capacity in k_merge (bucket size)
#define POISON_BASE ((int)0xAAAAAAAAu)

// ---- bf16 helpers: feature tables stored as bf16 (64 B/row), math in fp32 ----
__device__ inline unsigned bf16pack2(float a, float b) {
    unsigned ua = __float_as_uint(a);
    unsigned ub = __float_as_uint(b);
    ua = (ua + 0x7FFFu + ((ua >> 16) & 1)) >> 16;   // RNE
    ub = (ub + 0x7FFFu + ((ub >> 16) & 1)) >> 16;
    return ua | (ub << 16);
}
__device__ inline uint2 bf16pack4(float4 v) {
    return make_uint2(bf16pack2(v.x, v.y), bf16pack2(v.z, v.w));
}
__device__ inline float4 bf16unpack4(uint2 h) {
    return make_float4(__uint_as_float(h.x << 16),
                       __uint_as_float(h.x & 0xFFFF0000u),
                       __uint_as_float(h.y << 16),
                       __uint_as_float(h.y & 0xFFFF0000u));
}

// ---- shfl-based exclusive scan of LDS array arr[0..L), in place; returns total.
__device__ inline int lds_excl_scan(int* arr, int L, int* wsum, int t) {
    int carryv = 0;
    for (int base = 0; base < L; base += BS) {
        int idx = base + t;
        int v = (idx < L) ? arr[idx] : 0;
        int incl = v;
#pragma unroll
        for (int off = 1; off < 64; off <<= 1) {
            int u = __shfl_up(incl, off, 64);
            if ((t & 63) >= off) incl += u;
        }
        if ((t & 63) == 63) wsum[t >> 6] = incl;
        __syncthreads();
        int myw = t >> 6;
        int wpre = 0;
        if (myw > 0) wpre += wsum[0];
        if (myw > 1) wpre += wsum[1];
        if (myw > 2) wpre += wsum[2];
        int tot = wsum[0] + wsum[1] + wsum[2] + wsum[3];
        if (idx < L) arr[idx] = carryv + wpre + incl - v;
        __syncthreads();
        carryv += tot;
    }
    return carryv;
}

// ======== pass 1: block-local counting sort (+ fused layer-1 GEMM -> bf16 ht) ========
// also accumulates per-bucket totals into btot via global atomics (replaces k_trans).
__global__ void k_localsort_gemm(const int* __restrict__ dst, const int* __restrict__ src,
                                 const float* __restrict__ w, int* __restrict__ bc,
                                 int* __restrict__ locoff, int2* __restrict__ staged,
                                 int* __restrict__ btot,
                                 int E, int EPB, int NBUCK, int NBUCKP,
                                 const float* __restrict__ X, const float* __restrict__ Wm,
                                 uint2* __restrict__ H, int n) {
    __shared__ int    bins[MAXBUCK];
    __shared__ int    wsum[4];
    __shared__ int2   sbuf[SBUF_CAP];
    __shared__ float4 Ws[D * 8];
    int t = threadIdx.x;

    if ((int)blockIdx.x >= CBLK) {
        // ---- gemm1: H = X @ W1 (8 lanes/node; fp32 in, bf16 out, unscaled) ----
        for (int i = t; i < D * 8; i += BS) Ws[i] = ((const float4*)Wm)[i];
        __syncthreads();
        int gid  = (blockIdx.x - CBLK) * BS + t;
        int node = gid >> 3;
        int q    = gid & 7;
        if (node >= n) return;
        float4 xv  = ((const float4*)X)[node * 8 + q];
        float4 acc = make_float4(0.f, 0.f, 0.f, 0.f);
#pragma unroll
        for (int k = 0; k < D; ++k) {
            float comp = (k & 3) == 0 ? xv.x : (k & 3) == 1 ? xv.y
                       : (k & 3) == 2 ? xv.z : xv.w;
            float  xk = __shfl(comp, k >> 2, 8);
            float4 wr = Ws[k * 8 + q];
            acc.x += xk * wr.x; acc.y += xk * wr.y;
            acc.z += xk * wr.z; acc.w += xk * wr.w;
        }
        H[node * 8 + q] = bf16pack4(acc);
        return;
    }

    int blk = blockIdx.x;
    int beg = blk * EPB;
    int end = min(E, beg + EPB);
    int cnt = end - beg;
    for (int i = t; i < NBUCK; i += BS) bins[i] = 0;
    __syncthreads();

    // loop 1: histogram only (coalesced dst read, independent LDS atomics)
    for (int e = beg + t; e < end; e += BS)
        atomicAdd(&bins[dst[e] >> BSH], 1);
    __syncthreads();
    // counts out: block-major row + bucket-total accumulation (replaces transpose)
    for (int i = t; i < NBUCK; i += BS) {
        int v = bins[i];
        bc[blk * NBUCKP + i] = v;
        if (v) atomicAdd(&btot[i], v);
    }
    __syncthreads();
    // exclusive scan of bins in place (shfl-based, few barriers)
    lds_excl_scan(bins, NBUCK, wsum, t);
    for (int i = t; i < NBUCK; i += BS) locoff[blk * NBUCKP + i] = bins[i];
    __syncthreads();

    // loop 2: counting-sort placement into LDS (bins[b] advances as cursor)
    for (int e = beg + t; e < end; e += BS) {
        int dv  = dst[e];
        int b   = dv >> BSH;
        int pos = atomicAdd(&bins[b], 1);
        sbuf[pos] = make_int2(src[e] | ((dv & (BNODES - 1)) << 17), __float_as_int(w[e]));
    }
    __syncthreads();
    // coalesced copy out to own staging slice
    int2* myslice = staged + (size_t)blk * EPB;
    for (int i = t; i < cnt; i += BS) myslice[i] = sbuf[i];
}

// ======== pass 2: per-bucket merge (128 nodes) -> CSR + dinv + emeta + ht scaling ====
// reads bc/locoff COLUMNS directly (strided; L2-hot across adjacent blocks).
__global__ void k_merge(const int* __restrict__ bc, const int* __restrict__ locoff,
                        const int* __restrict__ btot, const int2* __restrict__ staged,
                        int2* __restrict__ emeta, int* __restrict__ rowptr,
                        float* __restrict__ dinv, uint2* __restrict__ H,
                        int N, int E, int NBUCK, int NBUCKP, int EPB) {
    __shared__ int2  ebuf[ECAP];
    __shared__ int   runoff[CBLK];
    __shared__ int   lrun[CBLK];
    __shared__ int   wsum[4];
    __shared__ int   ihist[BNODES];
    __shared__ float fdeg[BNODES];
    __shared__ int   cursor[BNODES];
    __shared__ float sdinv[BNODES];
    __shared__ int   hsum;
    int b = blockIdx.x, t = threadIdx.x;

    for (int k = t; k < CBLK; k += BS) {
        runoff[k] = bc[(size_t)k * NBUCKP + b];
        lrun[k]   = locoff[(size_t)k * NBUCKP + b];
    }
    if (t < BNODES) { ihist[t] = 0; fdeg[t] = 0.0f; }

    // bucket offset = sum btot[0..b): strided loads + shfl reduce (1 barrier)
    int pacc = 0;
    for (int k = t; k < b; k += BS) pacc += btot[k];
#pragma unroll
    for (int off = 32; off; off >>= 1) pacc += __shfl_down(pacc, off, 64);
    if ((t & 63) == 0) wsum[t >> 6] = pacc;
    __syncthreads();
    int bstart = wsum[0] + wsum[1] + wsum[2] + wsum[3];
    __syncthreads();                       // protect wsum before scan reuse

    int total = lds_excl_scan(runoff, CBLK, wsum, t);
    bool fits = total <= ECAP;

    // pass A: histogram + weighted degree (+ stage into LDS if it fits)
    if (fits) {
        for (int p = t; p < total; p += BS) {
            int lo = 0, hi = CBLK - 1;
            while (lo < hi) {
                int mid = (lo + hi + 1) >> 1;
                if (runoff[mid] <= p) lo = mid; else hi = mid - 1;
            }
            int2 v = staged[(size_t)lo * EPB + lrun[lo] + (p - runoff[lo])];
            int local = (v.x >> 17) & (BNODES - 1);
            atomicAdd(&ihist[local], 1);
            atomicAdd(&fdeg[local], __int_as_float(v.y));
            ebuf[p] = v;
        }
    } else {
        for (int k = t; k < CBLK; k += BS) {
            int gs = runoff[k];
            int ge = (k + 1 < CBLK) ? runoff[k + 1] : total;
            const int2* run = staged + (size_t)k * EPB + lrun[k];
            for (int j = 0; j < ge - gs; ++j) {
                int2 v = run[j];
                int local = (v.x >> 17) & (BNODES - 1);
                atomicAdd(&ihist[local], 1);
                atomicAdd(&fdeg[local], __int_as_float(v.y));
            }
        }
    }
    __syncthreads();
    // 128-bin exclusive scan: per-wave shfl scan + cross-wave fixup
    int v128 = 0, incl = 0;
    if (t < BNODES) {
        v128 = ihist[t];
        incl = v128;
#pragma unroll
        for (int off = 1; off < 64; off <<= 1) {
            int u = __shfl_up(incl, off, 64);
            if ((t & 63) >= off) incl += u;
        }
    }
    if (t == 63) hsum = incl;
    __syncthreads();
    if (t < BNODES) {
        if (t >= 64) incl += hsum;
        int excl = incl - v128;
        int node = b * BNODES + t;
        float di = rsqrtf(2.0f + fdeg[t]);
        if (node < N) {
            rowptr[node] = bstart + excl;
            dinv[node]   = di;
        }
        sdinv[t]  = di;
        cursor[t] = excl;
    }
    if (b == NBUCK - 1 && t == 0) rowptr[N] = E;
    __syncthreads();
    // scale this bucket's ht rows in place (row = 8 uint2 = 64 B)
    {
        int base_node = b * BNODES;
        for (int i = t; i < BNODES * 8; i += BS) {
            int row  = i >> 3;
            int node = base_node + row;
            if (node < N) {
                float di = sdinv[row];
                size_t off = (size_t)node * 8 + (i & 7);
                float4 f = bf16unpack4(H[off]);
                f.x *= di; f.y *= di; f.z *= di; f.w *= di;
                H[off] = bf16pack4(f);
            }
        }
    }
    __syncthreads();
    // pass B: cursor scatter into bucket-contiguous emeta (payload: clean src, raw w)
    if (fits) {
        for (int p = t; p < total; p += BS) {
            int2 v = ebuf[p];
            int local = (v.x >> 17) & (BNODES - 1);
            int r = atomicAdd(&cursor[local], 1);
            emeta[bstart + r] = make_int2(v.x & 0x1FFFF, v.y);
        }
    } else {
        for (int k = t; k < CBLK; k += BS) {
            int gs = runoff[k];
            int ge = (k + 1 < CBLK) ? runoff[k + 1] : total;
            const int2* run = staged + (size_t)k * EPB + lrun[k];
            for (int j = 0; j < ge - gs; ++j) {
                int2 v = run[j];
                int local = (v.x >> 17) & (BNODES - 1);
                int r = atomicAdd(&cursor[local], 1);
                emeta[bstart + r] = make_int2(v.x & 0x1FFFF, v.y);
            }
        }
    }
}

// ======== aggregates: 4 lanes/node, uint4 (16 B) gathers, next-chunk em prefetch ====
template <bool FUSE_GEMM>
__global__ void k_agg(const int* __restrict__ rowptr, const int2* __restrict__ emeta,
                      const uint4* __restrict__ Hs, const float* __restrict__ dinv,
                      const float* __restrict__ b, const float* __restrict__ W2,
                      void* __restrict__ outv, int n) {
    __shared__ float4 Ws[D * 8];
    int tid = threadIdx.x;
    if (FUSE_GEMM) {
        for (int i = tid; i < D * 8; i += BS) Ws[i] = ((const float4*)W2)[i];
        __syncthreads();
    }

    int gid  = blockIdx.x * BS + tid;
    int node = gid >> 2;
    int q    = gid & 3;                       // lane covers columns [8q, 8q+8)
    if (node >= n) return;

    float  di  = dinv[node];
    float4 bq0 = ((const float4*)b)[q * 2];
    float4 bq1 = ((const float4*)b)[q * 2 + 1];
    uint4  h0  = Hs[node * 4 + q];
    float4 a0  = bf16unpack4(make_uint2(h0.x, h0.y));
    float4 a1  = bf16unpack4(make_uint2(h0.z, h0.w));
    float4 acc0 = make_float4(2.f * a0.x, 2.f * a0.y, 2.f * a0.z, 2.f * a0.w);
    float4 acc1 = make_float4(2.f * a1.x, 2.f * a1.y, 2.f * a1.z, 2.f * a1.w);

    int beg  = rowptr[node];
    int end  = rowptr[node + 1];
    int full = beg + ((end - beg) & ~7);

    // software-pipelined: em loads for chunk i+1 issue before chunk i's gather/FMA
    int2 em0, em1;
    if (beg < full) { em0 = emeta[beg + q]; em1 = emeta[beg + 4 + q]; }
    for (int i0 = beg; i0 < full; i0 += 8) {
        int2 cem0 = em0, cem1 = em1;
        if (i0 + 8 < full) { em0 = emeta[i0 + 8 + q]; em1 = emeta[i0 + 12 + q]; }
        float nm0 = __int_as_float(cem0.y);
        float nm1 = __int_as_float(cem1.y);
#pragma unroll
        for (int j = 0; j < 4; ++j) {
            int   s  = __shfl(cem0.x, j, 4);
            float nm = __shfl(nm0, j, 4);
            uint4 hv = Hs[s * 4 + q];                     // 4 lanes -> 64B line
            float4 f0 = bf16unpack4(make_uint2(hv.x, hv.y));
            float4 f1 = bf16unpack4(make_uint2(hv.z, hv.w));
            acc0.x += nm * f0.x; acc0.y += nm * f0.y; acc0.z += nm * f0.z; acc0.w += nm * f0.w;
            acc1.x += nm * f1.x; acc1.y += nm * f1.y; acc1.z += nm * f1.z; acc1.w += nm * f1.w;
        }
#pragma unroll
        for (int j = 0; j < 4; ++j) {
            int   s  = __shfl(cem1.x, j, 4);
            float nm = __shfl(nm1, j, 4);
            uint4 hv = Hs[s * 4 + q];
            float4 f0 = bf16unpack4(make_uint2(hv.x, hv.y));
            float4 f1 = bf16unpack4(make_uint2(hv.z, hv.w));
            acc0.x += nm * f0.x; acc0.y += nm * f0.y; acc0.z += nm * f0.z; acc0.w += nm * f0.w;
            acc1.x += nm * f1.x; acc1.y += nm * f1.y; acc1.z += nm * f1.z; acc1.w += nm * f1.w;
        }
    }
    if (full < end) {
        int idx0 = full + q;
        int idx1 = full + 4 + q;
        int2 tm0 = (idx0 < end) ? emeta[idx0] : make_int2(0, 0);
        int2 tm1 = (idx1 < end) ? emeta[idx1] : make_int2(0, 0);
        float nm0 = (idx0 < end) ? __int_as_float(tm0.y) : 0.0f;
        float nm1 = (idx1 < end) ? __int_as_float(tm1.y) : 0.0f;
        int rem = end - full;
        int r0 = rem < 4 ? rem : 4;
        for (int j = 0; j < r0; ++j) {
            int   s  = __shfl(tm0.x, j, 4);
            float nm = __shfl(nm0, j, 4);
            uint4 hv = Hs[s * 4 + q];
            float4 f0 = bf16unpack4(make_uint2(hv.x, hv.y));
            float4 f1 = bf16unpack4(make_uint2(hv.z, hv.w));
            acc0.x += nm * f0.x; acc0.y += nm * f0.y; acc0.z += nm * f0.z; acc0.w += nm * f0.w;
            acc1.x += nm * f1.x; acc1.y += nm * f1.y; acc1.z += nm * f1.z; acc1.w += nm * f1.w;
        }
        for (int j = 0; j < rem - 4; ++j) {
            int   s  = __shfl(tm1.x, j, 4);
            float nm = __shfl(nm1, j, 4);
            uint4 hv = Hs[s * 4 + q];
            float4 f0 = bf16unpack4(make_uint2(hv.x, hv.y));
            float4 f1 = bf16unpack4(make_uint2(hv.z, hv.w));
            acc0.x += nm * f0.x; acc0.y += nm * f0.y; acc0.z += nm * f0.z; acc0.w += nm * f0.w;
            acc1.x += nm * f1.x; acc1.y += nm * f1.y; acc1.z += nm * f1.z; acc1.w += nm * f1.w;
        }
    }
    acc0.x = fmaxf(di * acc0.x + bq0.x, 0.f);
    acc0.y = fmaxf(di * acc0.y + bq0.y, 0.f);
    acc0.z = fmaxf(di * acc0.z + bq0.z, 0.f);
    acc0.w = fmaxf(di * acc0.w + bq0.w, 0.f);
    acc1.x = fmaxf(di * acc1.x + bq1.x, 0.f);
    acc1.y = fmaxf(di * acc1.y + bq1.y, 0.f);
    acc1.z = fmaxf(di * acc1.z + bq1.z, 0.f);
    acc1.w = fmaxf(di * acc1.w + bq1.w, 0.f);

    if (FUSE_GEMM) {
        float4 o0 = make_float4(0.f, 0.f, 0.f, 0.f);
        float4 o1 = make_float4(0.f, 0.f, 0.f, 0.f);
#pragma unroll
        for (int k = 0; k < D; ++k) {
            int sel = k & 7;
            float comp = sel == 0 ? acc0.x : sel == 1 ? acc0.y : sel == 2 ? acc0.z
                       : sel == 3 ? acc0.w : sel == 4 ? acc1.x : sel == 5 ? acc1.y
                       : sel == 6 ? acc1.z : acc1.w;
            float  hk = __shfl(comp, k >> 3, 4);
            float4 w0 = Ws[k * 8 + q * 2];
            float4 w1 = Ws[k * 8 + q * 2 + 1];
            o0.x += hk * w0.x; o0.y += hk * w0.y; o0.z += hk * w0.z; o0.w += hk * w0.w;
            o1.x += hk * w1.x; o1.y += hk * w1.y; o1.z += hk * w1.z; o1.w += hk * w1.w;
        }
        o0.x *= di; o0.y *= di; o0.z *= di; o0.w *= di;   // pre-scale for layer 2
        o1.x *= di; o1.y *= di; o1.z *= di; o1.w *= di;
        ((uint4*)outv)[node * 4 + q] =
            make_uint4(bf16pack2(o0.x, o0.y), bf16pack2(o0.z, o0.w),
                       bf16pack2(o1.x, o1.y), bf16pack2(o1.z, o1.w));
    } else {
        ((float4*)outv)[node * 8 + q * 2]     = acc0;
        ((float4*)outv)[node * 8 + q * 2 + 1] = acc1;
    }
}

// ======== fallback path (global-atomic hist; same scaled-table semantics) ========
__global__ void k_hist_gemm(const int4* __restrict__ dst4, int* __restrict__ cnt,
                            int4* __restrict__ rank4, int E4,
                            const float* __restrict__ X, const float* __restrict__ W,
                            uint2* __restrict__ H, int n, int gE4) {
    __shared__ float4 Ws[D * 8];
    int tid = threadIdx.x;
    if ((int)blockIdx.x < gE4) {
        int i = blockIdx.x * BS + tid;
        if (i >= E4) return;
        int4 d = dst4[i];
        int4 r;
        r.x = atomicAdd(&cnt[d.x], 1) - POISON_BASE;
        r.y = atomicAdd(&cnt[d.y], 1) - POISON_BASE;
        r.z = atomicAdd(&cnt[d.z], 1) - POISON_BASE;
        r.w = atomicAdd(&cnt[d.w], 1) - POISON_BASE;
        rank4[i] = r;
        return;
    }
    for (int i = tid; i < D * 8; i += BS) Ws[i] = ((const float4*)W)[i];
    __syncthreads();
    int gid  = (blockIdx.x - gE4) * BS + tid;
    int node = gid >> 3;
    int q    = gid & 7;
    if (node >= n) return;
    float4 xv  = ((const float4*)X)[node * 8 + q];
    float4 acc = make_float4(0.f, 0.f, 0.f, 0.f);
#pragma unroll
    for (int k = 0; k < D; ++k) {
        float comp = (k & 3) == 0 ? xv.x : (k & 3) == 1 ? xv.y
                   : (k & 3) == 2 ? xv.z : xv.w;
        float  xk = __shfl(comp, k >> 2, 8);
        float4 wr = Ws[k * 8 + q];
        acc.x += xk * wr.x; acc.y += xk * wr.y;
        acc.z += xk * wr.z; acc.w += xk * wr.w;
    }
    H[node * 8 + q] = bf16pack4(acc);
}

__global__ void k_scan1(const int* __restrict__ cnt, int* __restrict__ bsum, int n) {
    __shared__ int s[BS];
    int t = threadIdx.x, i = blockIdx.x * BS + t;
    s[t] = (i < n) ? (cnt[i] - POISON_BASE) : 0;
    __syncthreads();
    for (int off = BS / 2; off > 0; off >>= 1) {
        if (t < off) s[t] += s[t + off];
        __syncthreads();
    }
    if (t == 0) bsum[blockIdx.x] = s[0];
}

__global__ void k_scan23(const int* __restrict__ cnt, const int* __restrict__ bsum,
                         int* __restrict__ rowptr, int n) {
    __shared__ int red[BS];
    __shared__ int s[BS];
    int t = threadIdx.x, i = blockIdx.x * BS + t;
    int pacc = 0;
    for (int k = t; k < (int)blockIdx.x; k += BS) pacc += bsum[k];
    red[t] = pacc;
    __syncthreads();
    for (int off = BS / 2; off > 0; off >>= 1) {
        if (t < off) red[t] += red[t + off];
        __syncthreads();
    }
    int bpre = red[0];
    int v = (i < n) ? (cnt[i] - POISON_BASE) : 0;
    s[t] = v;
    __syncthreads();
    for (int off = 1; off < BS; off <<= 1) {
        int u = (t >= off) ? s[t - off] : 0;
        __syncthreads();
        s[t] += u;
        __syncthreads();
    }
    if (i < n) {
        int excl = bpre + s[t] - v;
        rowptr[i] = excl;
        if (i == n - 1) rowptr[n] = excl + v;
    }
}

__global__ void k_reorder(const int4* __restrict__ src4, const int4* __restrict__ dst4,
                          const float4* __restrict__ w4, const int4* __restrict__ rank4,
                          const int* __restrict__ rowptr, int2* __restrict__ emeta, int E4) {
    int i = blockIdx.x * blockDim.x + threadIdx.x;
    if (i >= E4) return;
    int4   s = src4[i];
    int4   d = dst4[i];
    float4 w = w4[i];
    int4   r = rank4[i];
    emeta[rowptr[d.x] + r.x] = make_int2(s.x, __float_as_int(w.x));
    emeta[rowptr[d.y] + r.y] = make_int2(s.y, __float_as_int(w.y));
    emeta[rowptr[d.z] + r.z] = make_int2(s.z, __float_as_int(w.z));
    emeta[rowptr[d.w] + r.w] = make_int2(s.w, __float_as_int(w.w));
}

__global__ void k_degscaleF(const int* __restrict__ rowptr, const int2* __restrict__ emeta,
                            float* __restrict__ dinv, uint2* __restrict__ H, int n) {
    int gid  = blockIdx.x * blockDim.x + threadIdx.x;
    int node = gid >> 3;
    int c    = gid & 7;
    if (node >= n) return;
    int beg = rowptr[node], end = rowptr[node + 1];
    float sum = 0.0f;
    for (int idx = beg + c; idx < end; idx += 8)
        sum += __int_as_float(emeta[idx].y);
    sum += __shfl_xor(sum, 4, 8);
    sum += __shfl_xor(sum, 2, 8);
    sum += __shfl_xor(sum, 1, 8);
    float di = rsqrtf(2.0f + sum);
    if (c == 0) dinv[node] = di;
    di = __shfl(di, 0, 8);
    size_t off = (size_t)node * 8 + c;
    float4 f = bf16unpack4(H[off]);
    f.x *= di; f.y *= di; f.z *= di; f.w *= di;
    H[off] = bf16pack4(f);
}

// ======== launch ========
extern "C" void kernel_launch(void* const* d_in, const int* in_sizes, int n_in,
                              void* d_out, int out_size, void* d_ws, size_t ws_size,
                              hipStream_t stream) {
    const float* x   = (const float*)d_in[0];
    const int*   ei  = (const int*)d_in[1];
    const float* w   = (const float*)d_in[2];
    const float* W1  = (const float*)d_in[3];
    const float* b1  = (const float*)d_in[4];
    const float* W2  = (const float*)d_in[5];
    const float* b2  = (const float*)d_in[6];
    float*       out = (float*)d_out;

    const int N = in_sizes[0] / D;       // 100000
    const int E = in_sizes[2];           // 1600000
    const int* src = ei;
    const int* dst = ei + E;

    const int NBUCK  = (N + BNODES - 1) / BNODES;    // 782
    const int NBUCKP = (NBUCK + 3) & ~3;             // 784
    const int EPB    = (E + CBLK - 1) / CBLK;        // 1600
    const int NB     = (N + BS - 1) / BS;
    const int E4     = E / 4;
    const int gE4    = (E4 + BS - 1) / BS;
    const int gN8    = (N * 8 + BS - 1) / BS;        // 3125
    const int gN4    = (N * 4 + BS - 1) / BS;        // 1563

    // ---- workspace layout (all segments 16B-aligned) ----
    char*  base    = (char*)d_ws;
    int2*  emeta   = (int2*)base;                                  // E*8
    uint2* ht      = (uint2*)(base + (size_t)E * 8);               // N*8 uint2 (64B/row)
    uint2* ht2     = ht + (size_t)N * 8;                           // N*8 uint2
    float* dinv    = (float*)(ht2 + (size_t)N * 8);                // N*4
    int*   rowptr  = (int*)(dinv + N);                             // (N+4)&~3 ints
    int2*  staged  = (int2*)(rowptr + ((N + 4) & ~3));             // E*8
    int*   bc      = (int*)(staged + E);                           // CBLK*NBUCKP ints
    int*   locoff  = bc + (size_t)CBLK * NBUCKP;                   // CBLK*NBUCKP ints
    int*   btot    = locoff + (size_t)CBLK * NBUCKP;               // NBUCKP ints
    size_t need    = (size_t)((char*)(btot + NBUCKP) - base);

    bool main_ok = (ws_size >= need) && (NBUCK <= MAXBUCK) && (N < (1 << 17)) &&
                   (EPB <= SBUF_CAP) && (N % 4 == 0);

    if (main_ok) {
        // ---- CSR build: memset + localsort(+btot) + merge (k_trans folded away) ----
        hipMemsetAsync(btot, 0, (size_t)NBUCKP * 4, stream);       // graph-capture-safe
        k_localsort_gemm<<<CBLK + gN8, BS, 0, stream>>>(dst, src, w, bc, locoff, staged,
                                                        btot, E, EPB, NBUCK, NBUCKP,
                                                        x, W1, ht, N);
        k_merge<<<NBUCK, BS, 0, stream>>>(bc, locoff, btot, staged, emeta, rowptr, dinv,
                                          ht, N, E, NBUCK, NBUCKP, EPB);
        // ---- layers over pre-scaled tables (4-lane uint4 gathers, em prefetch) ----
        k_agg<true ><<<gN4, BS, 0, stream>>>(rowptr, emeta, (const uint4*)ht,  dinv, b1, W2, ht2, N);
        k_agg<false><<<gN4, BS, 0, stream>>>(rowptr, emeta, (const uint4*)ht2, dinv, b2, nullptr, out, N);
    } else {
        // ---- fallback: global-atomic hist path (same scaled-table semantics) ----
        int* cnt  = (int*)staged;             // N ints (start at POISON_BASE)
        int* rank = cnt + N;                  // E ints
        int* bsum = rank + E;                 // NB ints
        k_hist_gemm<<<gE4 + gN8, BS, 0, stream>>>((const int4*)dst, cnt, (int4*)rank, E4,
                                                  x, W1, ht, N, gE4);
        k_scan1 <<<NB, BS, 0, stream>>>(cnt, bsum, N);
        k_scan23<<<NB, BS, 0, stream>>>(cnt, bsum, rowptr, N);
        k_reorder<<<(E4 + BS - 1) / BS, BS, 0, stream>>>((const int4*)src, (const int4*)dst,
                                                         (const float4*)w, (const int4*)rank,
                                                         rowptr, emeta, E4);
        k_degscaleF<<<gN8, BS, 0, stream>>>(rowptr, emeta, dinv, ht, N);
        k_agg<true ><<<gN4, BS, 0, stream>>>(rowptr, emeta, (const uint4*)ht,  dinv, b1, W2, ht2, N);
        k_agg<false><<<gN4, BS, 0, stream>>>(rowptr, emeta, (const uint4*)ht2, dinv, b2, nullptr, out, N);
    }
}

// Round 5
// 183.598 us; speedup vs baseline: 1.2265x; 1.2265x over previous
//
#include <hip/hip_runtime.h>

#define D       32
#define BS      256
#define CBLK    500          // edge-chunk blocks for the local-sort pass
#define CBLKP   500          // run-table row length
#define BSH     7            // bucket shift: 128 nodes per bucket
#define BNODES  128
#define MAXBUCK 1024         // LDS histogram capacity (NBUCK = ceil(N/128) must fit)
#define SBUF_CAP 3584        // LDS staging capacity in pass 1 (EPB must fit)
#define ECAP    2560         // LDS edge-buffer capacity in k_merge (bucket max ~2200)
#define POISON_BASE ((int)0xAAAAAAAAu)

// ---- bf16 helpers: feature tables stored as bf16 (64 B/row), math in fp32 ----
__device__ inline unsigned bf16pack2(float a, float b) {
    unsigned ua = __float_as_uint(a);
    unsigned ub = __float_as_uint(b);
    ua = (ua + 0x7FFFu + ((ua >> 16) & 1)) >> 16;   // RNE
    ub = (ub + 0x7FFFu + ((ub >> 16) & 1)) >> 16;
    return ua | (ub << 16);
}
__device__ inline uint2 bf16pack4(float4 v) {
    return make_uint2(bf16pack2(v.x, v.y), bf16pack2(v.z, v.w));
}
__device__ inline float4 bf16unpack4(uint2 h) {
    return make_float4(__uint_as_float(h.x << 16),
                       __uint_as_float(h.x & 0xFFFF0000u),
                       __uint_as_float(h.y << 16),
                       __uint_as_float(h.y & 0xFFFF0000u));
}

// ---- shfl-based exclusive scan of LDS array arr[0..L), in place; returns total.
__device__ inline int lds_excl_scan(int* arr, int L, int* wsum, int t) {
    int carryv = 0;
    for (int base = 0; base < L; base += BS) {
        int idx = base + t;
        int v = (idx < L) ? arr[idx] : 0;
        int incl = v;
#pragma unroll
        for (int off = 1; off < 64; off <<= 1) {
            int u = __shfl_up(incl, off, 64);
            if ((t & 63) >= off) incl += u;
        }
        if ((t & 63) == 63) wsum[t >> 6] = incl;
        __syncthreads();
        int myw = t >> 6;
        int wpre = 0;
        if (myw > 0) wpre += wsum[0];
        if (myw > 1) wpre += wsum[1];
        if (myw > 2) wpre += wsum[2];
        int tot = wsum[0] + wsum[1] + wsum[2] + wsum[3];
        if (idx < L) arr[idx] = carryv + wpre + incl - v;
        __syncthreads();
        carryv += tot;
    }
    return carryv;
}

// ======== pass 1: block-local counting sort (+ fused layer-1 GEMM -> bf16 ht) ========
__global__ void k_localsort_gemm(const int* __restrict__ dst, const int* __restrict__ src,
                                 const float* __restrict__ w, int* __restrict__ bc,
                                 int* __restrict__ locoff, int2* __restrict__ staged,
                                 int E, int EPB, int NBUCK, int NBUCKP,
                                 const float* __restrict__ X, const float* __restrict__ Wm,
                                 uint2* __restrict__ H, int n) {
    __shared__ int    bins[MAXBUCK];
    __shared__ int    wsum[4];
    __shared__ int2   sbuf[SBUF_CAP];
    __shared__ float4 Ws[D * 8];
    int t = threadIdx.x;

    if ((int)blockIdx.x >= CBLK) {
        // ---- gemm1: H = X @ W1 (8 lanes/node; fp32 in, bf16 out, unscaled) ----
        for (int i = t; i < D * 8; i += BS) Ws[i] = ((const float4*)Wm)[i];
        __syncthreads();
        int gid  = (blockIdx.x - CBLK) * BS + t;
        int node = gid >> 3;
        int q    = gid & 7;
        if (node >= n) return;
        float4 xv  = ((const float4*)X)[node * 8 + q];
        float4 acc = make_float4(0.f, 0.f, 0.f, 0.f);
#pragma unroll
        for (int k = 0; k < D; ++k) {
            float comp = (k & 3) == 0 ? xv.x : (k & 3) == 1 ? xv.y
                       : (k & 3) == 2 ? xv.z : xv.w;
            float  xk = __shfl(comp, k >> 2, 8);
            float4 wr = Ws[k * 8 + q];
            acc.x += xk * wr.x; acc.y += xk * wr.y;
            acc.z += xk * wr.z; acc.w += xk * wr.w;
        }
        H[node * 8 + q] = bf16pack4(acc);
        return;
    }

    int blk = blockIdx.x;
    int beg = blk * EPB;
    int end = min(E, beg + EPB);
    int cnt = end - beg;
    for (int i = t; i < NBUCK; i += BS) bins[i] = 0;
    __syncthreads();

    // loop 1: histogram only (coalesced dst read, independent LDS atomics)
    for (int e = beg + t; e < end; e += BS)
        atomicAdd(&bins[dst[e] >> BSH], 1);
    __syncthreads();
    // counts out: block-major contiguous run
    for (int i = t; i < NBUCK; i += BS) bc[blk * NBUCKP + i] = bins[i];
    __syncthreads();
    // exclusive scan of bins in place (shfl-based, few barriers)
    lds_excl_scan(bins, NBUCK, wsum, t);
    for (int i = t; i < NBUCK; i += BS) locoff[blk * NBUCKP + i] = bins[i];
    __syncthreads();

    // loop 2: counting-sort placement into LDS (bins[b] advances as cursor)
    for (int e = beg + t; e < end; e += BS) {
        int dv  = dst[e];
        int b   = dv >> BSH;
        int pos = atomicAdd(&bins[b], 1);
        sbuf[pos] = make_int2(src[e] | ((dv & (BNODES - 1)) << 17), __float_as_int(w[e]));
    }
    __syncthreads();
    // coalesced copy out to own staging slice
    int2* myslice = staged + (size_t)blk * EPB;
    for (int i = t; i < cnt; i += BS) myslice[i] = sbuf[i];
}

// ======== transpose (block-major -> bucket-major) + bucket totals ========
__global__ void k_trans(const int* __restrict__ bc, const int* __restrict__ locoff,
                        int* __restrict__ bcT, int* __restrict__ locoffT,
                        int* __restrict__ btot, int NBUCK, int NBUCKP) {
    __shared__ int tile[32][33];
    const int* in  = (blockIdx.z == 0) ? bc  : locoff;
    int*       out = (blockIdx.z == 0) ? bcT : locoffT;
    int c0 = blockIdx.x * 32;              // bucket base
    int r0 = blockIdx.y * 32;              // sort-block base
    int tx = threadIdx.x & 31, ty = threadIdx.x >> 5;
    for (int dy = ty; dy < 32; dy += 8) {
        int r = r0 + dy, c = c0 + tx;
        tile[dy][tx] = (r < CBLK && c < NBUCK) ? in[r * NBUCKP + c] : 0;
    }
    __syncthreads();
    for (int dy = ty; dy < 32; dy += 8) {
        int c = c0 + dy, r = r0 + tx;
        if (c < NBUCK && r < CBLK) out[c * CBLKP + r] = tile[tx][dy];
    }
    if (blockIdx.z == 0 && ty == 0 && c0 + tx < NBUCK) {
        int s = 0;
#pragma unroll
        for (int dy = 0; dy < 32; ++dy) s += tile[dy][tx];
        if (s) atomicAdd(&btot[c0 + tx], s);
    }
}

// ======== pass 3: per-bucket merge (128 nodes) -> CSR + dinv + emeta + ht scaling ====
// pass A software-pipelined: next staged gather issues before current LDS atomics.
__global__ void k_merge(const int* __restrict__ bcT, const int* __restrict__ locoffT,
                        const int* __restrict__ btot, const int2* __restrict__ staged,
                        int2* __restrict__ emeta, int* __restrict__ rowptr,
                        float* __restrict__ dinv, uint2* __restrict__ H,
                        int N, int E, int NBUCK, int EPB) {
    __shared__ int2  ebuf[ECAP];
    __shared__ int   runoff[CBLK];
    __shared__ int   lrun[CBLK];
    __shared__ int   wsum[4];
    __shared__ int   ihist[BNODES];
    __shared__ float fdeg[BNODES];
    __shared__ int   cursor[BNODES];
    __shared__ float sdinv[BNODES];
    __shared__ int   hsum;
    int b = blockIdx.x, t = threadIdx.x;

    for (int k = t; k < CBLK; k += BS) {
        runoff[k] = bcT[b * CBLKP + k];
        lrun[k]   = locoffT[b * CBLKP + k];
    }
    if (t < BNODES) { ihist[t] = 0; fdeg[t] = 0.0f; }

    // bucket offset = sum btot[0..b): strided loads + shfl reduce (1 barrier)
    int pacc = 0;
    for (int k = t; k < b; k += BS) pacc += btot[k];
#pragma unroll
    for (int off = 32; off; off >>= 1) pacc += __shfl_down(pacc, off, 64);
    if ((t & 63) == 0) wsum[t >> 6] = pacc;
    __syncthreads();
    int bstart = wsum[0] + wsum[1] + wsum[2] + wsum[3];
    __syncthreads();                       // protect wsum before scan reuse

    int total = lds_excl_scan(runoff, CBLK, wsum, t);
    bool fits = total <= ECAP;

    // pass A: histogram + weighted degree (+ stage into LDS if it fits)
    if (fits) {
        int2 vnext = make_int2(0, 0);
        if (t < total) {
            int lo = 0, hi = CBLK - 1;
            while (lo < hi) {
                int mid = (lo + hi + 1) >> 1;
                if (runoff[mid] <= t) lo = mid; else hi = mid - 1;
            }
            vnext = staged[(size_t)lo * EPB + lrun[lo] + (t - runoff[lo])];
        }
        for (int p = t; p < total; p += BS) {
            int2 v = vnext;
            int pn = p + BS;
            if (pn < total) {
                int lo = 0, hi = CBLK - 1;
                while (lo < hi) {
                    int mid = (lo + hi + 1) >> 1;
                    if (runoff[mid] <= pn) lo = mid; else hi = mid - 1;
                }
                vnext = staged[(size_t)lo * EPB + lrun[lo] + (pn - runoff[lo])];
            }
            int local = (v.x >> 17) & (BNODES - 1);
            atomicAdd(&ihist[local], 1);
            atomicAdd(&fdeg[local], __int_as_float(v.y));
            ebuf[p] = v;
        }
    } else {
        for (int k = t; k < CBLK; k += BS) {
            int gs = runoff[k];
            int ge = (k + 1 < CBLK) ? runoff[k + 1] : total;
            const int2* run = staged + (size_t)k * EPB + lrun[k];
            for (int j = 0; j < ge - gs; ++j) {
                int2 v = run[j];
                int local = (v.x >> 17) & (BNODES - 1);
                atomicAdd(&ihist[local], 1);
                atomicAdd(&fdeg[local], __int_as_float(v.y));
            }
        }
    }
    __syncthreads();
    // 128-bin exclusive scan: per-wave shfl scan + cross-wave fixup
    int v128 = 0, incl = 0;
    if (t < BNODES) {
        v128 = ihist[t];
        incl = v128;
#pragma unroll
        for (int off = 1; off < 64; off <<= 1) {
            int u = __shfl_up(incl, off, 64);
            if ((t & 63) >= off) incl += u;
        }
    }
    if (t == 63) hsum = incl;
    __syncthreads();
    if (t < BNODES) {
        if (t >= 64) incl += hsum;
        int excl = incl - v128;
        int node = b * BNODES + t;
        float di = rsqrtf(2.0f + fdeg[t]);
        if (node < N) {
            rowptr[node] = bstart + excl;
            dinv[node]   = di;
        }
        sdinv[t]  = di;
        cursor[t] = excl;
    }
    if (b == NBUCK - 1 && t == 0) rowptr[N] = E;
    __syncthreads();
    // scale this bucket's ht rows in place (row = 8 uint2 = 64 B)
    {
        int base_node = b * BNODES;
        for (int i = t; i < BNODES * 8; i += BS) {
            int row  = i >> 3;
            int node = base_node + row;
            if (node < N) {
                float di = sdinv[row];
                size_t off = (size_t)node * 8 + (i & 7);
                float4 f = bf16unpack4(H[off]);
                f.x *= di; f.y *= di; f.z *= di; f.w *= di;
                H[off] = bf16pack4(f);
            }
        }
    }
    __syncthreads();
    // pass B: cursor scatter into bucket-contiguous emeta (payload: clean src, raw w)
    if (fits) {
        for (int p = t; p < total; p += BS) {
            int2 v = ebuf[p];
            int local = (v.x >> 17) & (BNODES - 1);
            int r = atomicAdd(&cursor[local], 1);
            emeta[bstart + r] = make_int2(v.x & 0x1FFFF, v.y);
        }
    } else {
        for (int k = t; k < CBLK; k += BS) {
            int gs = runoff[k];
            int ge = (k + 1 < CBLK) ? runoff[k + 1] : total;
            const int2* run = staged + (size_t)k * EPB + lrun[k];
            for (int j = 0; j < ge - gs; ++j) {
                int2 v = run[j];
                int local = (v.x >> 17) & (BNODES - 1);
                int r = atomicAdd(&cursor[local], 1);
                emeta[bstart + r] = make_int2(v.x & 0x1FFFF, v.y);
            }
        }
    }
}

// ======== aggregates: 4 lanes/node, uint4 (16 B) gathers, next-chunk em prefetch ====
template <bool FUSE_GEMM>
__global__ void k_agg(const int* __restrict__ rowptr, const int2* __restrict__ emeta,
                      const uint4* __restrict__ Hs, const float* __restrict__ dinv,
                      const float* __restrict__ b, const float* __restrict__ W2,
                      void* __restrict__ outv, int n) {
    __shared__ float4 Ws[D * 8];
    int tid = threadIdx.x;
    if (FUSE_GEMM) {
        for (int i = tid; i < D * 8; i += BS) Ws[i] = ((const float4*)W2)[i];
        __syncthreads();
    }

    int gid  = blockIdx.x * BS + tid;
    int node = gid >> 2;
    int q    = gid & 3;                       // lane covers columns [8q, 8q+8)
    if (node >= n) return;

    float  di  = dinv[node];
    float4 bq0 = ((const float4*)b)[q * 2];
    float4 bq1 = ((const float4*)b)[q * 2 + 1];
    uint4  h0  = Hs[node * 4 + q];
    float4 a0  = bf16unpack4(make_uint2(h0.x, h0.y));
    float4 a1  = bf16unpack4(make_uint2(h0.z, h0.w));
    float4 acc0 = make_float4(2.f * a0.x, 2.f * a0.y, 2.f * a0.z, 2.f * a0.w);
    float4 acc1 = make_float4(2.f * a1.x, 2.f * a1.y, 2.f * a1.z, 2.f * a1.w);

    int beg  = rowptr[node];
    int end  = rowptr[node + 1];
    int full = beg + ((end - beg) & ~7);

    // software-pipelined: em loads for chunk i+1 issue before chunk i's gather/FMA
    int2 em0, em1;
    if (beg < full) { em0 = emeta[beg + q]; em1 = emeta[beg + 4 + q]; }
    for (int i0 = beg; i0 < full; i0 += 8) {
        int2 cem0 = em0, cem1 = em1;
        if (i0 + 8 < full) { em0 = emeta[i0 + 8 + q]; em1 = emeta[i0 + 12 + q]; }
        float nm0 = __int_as_float(cem0.y);
        float nm1 = __int_as_float(cem1.y);
#pragma unroll
        for (int j = 0; j < 4; ++j) {
            int   s  = __shfl(cem0.x, j, 4);
            float nm = __shfl(nm0, j, 4);
            uint4 hv = Hs[s * 4 + q];                     // 4 lanes -> 64B line
            float4 f0 = bf16unpack4(make_uint2(hv.x, hv.y));
            float4 f1 = bf16unpack4(make_uint2(hv.z, hv.w));
            acc0.x += nm * f0.x; acc0.y += nm * f0.y; acc0.z += nm * f0.z; acc0.w += nm * f0.w;
            acc1.x += nm * f1.x; acc1.y += nm * f1.y; acc1.z += nm * f1.z; acc1.w += nm * f1.w;
        }
#pragma unroll
        for (int j = 0; j < 4; ++j) {
            int   s  = __shfl(cem1.x, j, 4);
            float nm = __shfl(nm1, j, 4);
            uint4 hv = Hs[s * 4 + q];
            float4 f0 = bf16unpack4(make_uint2(hv.x, hv.y));
            float4 f1 = bf16unpack4(make_uint2(hv.z, hv.w));
            acc0.x += nm * f0.x; acc0.y += nm * f0.y; acc0.z += nm * f0.z; acc0.w += nm * f0.w;
            acc1.x += nm * f1.x; acc1.y += nm * f1.y; acc1.z += nm * f1.z; acc1.w += nm * f1.w;
        }
    }
    if (full < end) {
        int idx0 = full + q;
        int idx1 = full + 4 + q;
        int2 tm0 = (idx0 < end) ? emeta[idx0] : make_int2(0, 0);
        int2 tm1 = (idx1 < end) ? emeta[idx1] : make_int2(0, 0);
        float nm0 = (idx0 < end) ? __int_as_float(tm0.y) : 0.0f;
        float nm1 = (idx1 < end) ? __int_as_float(tm1.y) : 0.0f;
        int rem = end - full;
        int r0 = rem < 4 ? rem : 4;
        for (int j = 0; j < r0; ++j) {
            int   s  = __shfl(tm0.x, j, 4);
            float nm = __shfl(nm0, j, 4);
            uint4 hv = Hs[s * 4 + q];
            float4 f0 = bf16unpack4(make_uint2(hv.x, hv.y));
            float4 f1 = bf16unpack4(make_uint2(hv.z, hv.w));
            acc0.x += nm * f0.x; acc0.y += nm * f0.y; acc0.z += nm * f0.z; acc0.w += nm * f0.w;
            acc1.x += nm * f1.x; acc1.y += nm * f1.y; acc1.z += nm * f1.z; acc1.w += nm * f1.w;
        }
        for (int j = 0; j < rem - 4; ++j) {
            int   s  = __shfl(tm1.x, j, 4);
            float nm = __shfl(nm1, j, 4);
            uint4 hv = Hs[s * 4 + q];
            float4 f0 = bf16unpack4(make_uint2(hv.x, hv.y));
            float4 f1 = bf16unpack4(make_uint2(hv.z, hv.w));
            acc0.x += nm * f0.x; acc0.y += nm * f0.y; acc0.z += nm * f0.z; acc0.w += nm * f0.w;
            acc1.x += nm * f1.x; acc1.y += nm * f1.y; acc1.z += nm * f1.z; acc1.w += nm * f1.w;
        }
    }
    acc0.x = fmaxf(di * acc0.x + bq0.x, 0.f);
    acc0.y = fmaxf(di * acc0.y + bq0.y, 0.f);
    acc0.z = fmaxf(di * acc0.z + bq0.z, 0.f);
    acc0.w = fmaxf(di * acc0.w + bq0.w, 0.f);
    acc1.x = fmaxf(di * acc1.x + bq1.x, 0.f);
    acc1.y = fmaxf(di * acc1.y + bq1.y, 0.f);
    acc1.z = fmaxf(di * acc1.z + bq1.z, 0.f);
    acc1.w = fmaxf(di * acc1.w + bq1.w, 0.f);

    if (FUSE_GEMM) {
        float4 o0 = make_float4(0.f, 0.f, 0.f, 0.f);
        float4 o1 = make_float4(0.f, 0.f, 0.f, 0.f);
#pragma unroll
        for (int k = 0; k < D; ++k) {
            int sel = k & 7;
            float comp = sel == 0 ? acc0.x : sel == 1 ? acc0.y : sel == 2 ? acc0.z
                       : sel == 3 ? acc0.w : sel == 4 ? acc1.x : sel == 5 ? acc1.y
                       : sel == 6 ? acc1.z : acc1.w;
            float  hk = __shfl(comp, k >> 3, 4);
            float4 w0 = Ws[k * 8 + q * 2];
            float4 w1 = Ws[k * 8 + q * 2 + 1];
            o0.x += hk * w0.x; o0.y += hk * w0.y; o0.z += hk * w0.z; o0.w += hk * w0.w;
            o1.x += hk * w1.x; o1.y += hk * w1.y; o1.z += hk * w1.z; o1.w += hk * w1.w;
        }
        o0.x *= di; o0.y *= di; o0.z *= di; o0.w *= di;   // pre-scale for layer 2
        o1.x *= di; o1.y *= di; o1.z *= di; o1.w *= di;
        ((uint4*)outv)[node * 4 + q] =
            make_uint4(bf16pack2(o0.x, o0.y), bf16pack2(o0.z, o0.w),
                       bf16pack2(o1.x, o1.y), bf16pack2(o1.z, o1.w));
    } else {
        ((float4*)outv)[node * 8 + q * 2]     = acc0;
        ((float4*)outv)[node * 8 + q * 2 + 1] = acc1;
    }
}

// ======== fallback path (global-atomic hist; same scaled-table semantics) ========
__global__ void k_hist_gemm(const int4* __restrict__ dst4, int* __restrict__ cnt,
                            int4* __restrict__ rank4, int E4,
                            const float* __restrict__ X, const float* __restrict__ W,
                            uint2* __restrict__ H, int n, int gE4) {
    __shared__ float4 Ws[D * 8];
    int tid = threadIdx.x;
    if ((int)blockIdx.x < gE4) {
        int i = blockIdx.x * BS + tid;
        if (i >= E4) return;
        int4 d = dst4[i];
        int4 r;
        r.x = atomicAdd(&cnt[d.x], 1) - POISON_BASE;
        r.y = atomicAdd(&cnt[d.y], 1) - POISON_BASE;
        r.z = atomicAdd(&cnt[d.z], 1) - POISON_BASE;
        r.w = atomicAdd(&cnt[d.w], 1) - POISON_BASE;
        rank4[i] = r;
        return;
    }
    for (int i = tid; i < D * 8; i += BS) Ws[i] = ((const float4*)W)[i];
    __syncthreads();
    int gid  = (blockIdx.x - gE4) * BS + tid;
    int node = gid >> 3;
    int q    = gid & 7;
    if (node >= n) return;
    float4 xv  = ((const float4*)X)[node * 8 + q];
    float4 acc = make_float4(0.f, 0.f, 0.f, 0.f);
#pragma unroll
    for (int k = 0; k < D; ++k) {
        float comp = (k & 3) == 0 ? xv.x : (k & 3) == 1 ? xv.y
                   : (k & 3) == 2 ? xv.z : xv.w;
        float  xk = __shfl(comp, k >> 2, 8);
        float4 wr = Ws[k * 8 + q];
        acc.x += xk * wr.x; acc.y += xk * wr.y;
        acc.z += xk * wr.z; acc.w += xk * wr.w;
    }
    H[node * 8 + q] = bf16pack4(acc);
}

__global__ void k_scan1(const int* __restrict__ cnt, int* __restrict__ bsum, int n) {
    __shared__ int s[BS];
    int t = threadIdx.x, i = blockIdx.x * BS + t;
    s[t] = (i < n) ? (cnt[i] - POISON_BASE) : 0;
    __syncthreads();
    for (int off = BS / 2; off > 0; off >>= 1) {
        if (t < off) s[t] += s[t + off];
        __syncthreads();
    }
    if (t == 0) bsum[blockIdx.x] = s[0];
}

__global__ void k_scan23(const int* __restrict__ cnt, const int* __restrict__ bsum,
                         int* __restrict__ rowptr, int n) {
    __shared__ int red[BS];
    __shared__ int s[BS];
    int t = threadIdx.x, i = blockIdx.x * BS + t;
    int pacc = 0;
    for (int k = t; k < (int)blockIdx.x; k += BS) pacc += bsum[k];
    red[t] = pacc;
    __syncthreads();
    for (int off = BS / 2; off > 0; off >>= 1) {
        if (t < off) red[t] += red[t + off];
        __syncthreads();
    }
    int bpre = red[0];
    int v = (i < n) ? (cnt[i] - POISON_BASE) : 0;
    s[t] = v;
    __syncthreads();
    for (int off = 1; off < BS; off <<= 1) {
        int u = (t >= off) ? s[t - off] : 0;
        __syncthreads();
        s[t] += u;
        __syncthreads();
    }
    if (i < n) {
        int excl = bpre + s[t] - v;
        rowptr[i] = excl;
        if (i == n - 1) rowptr[n] = excl + v;
    }
}

__global__ void k_reorder(const int4* __restrict__ src4, const int4* __restrict__ dst4,
                          const float4* __restrict__ w4, const int4* __restrict__ rank4,
                          const int* __restrict__ rowptr, int2* __restrict__ emeta, int E4) {
    int i = blockIdx.x * blockDim.x + threadIdx.x;
    if (i >= E4) return;
    int4   s = src4[i];
    int4   d = dst4[i];
    float4 w = w4[i];
    int4   r = rank4[i];
    emeta[rowptr[d.x] + r.x] = make_int2(s.x, __float_as_int(w.x));
    emeta[rowptr[d.y] + r.y] = make_int2(s.y, __float_as_int(w.y));
    emeta[rowptr[d.z] + r.z] = make_int2(s.z, __float_as_int(w.z));
    emeta[rowptr[d.w] + r.w] = make_int2(s.w, __float_as_int(w.w));
}

__global__ void k_degscaleF(const int* __restrict__ rowptr, const int2* __restrict__ emeta,
                            float* __restrict__ dinv, uint2* __restrict__ H, int n) {
    int gid  = blockIdx.x * blockDim.x + threadIdx.x;
    int node = gid >> 3;
    int c    = gid & 7;
    if (node >= n) return;
    int beg = rowptr[node], end = rowptr[node + 1];
    float sum = 0.0f;
    for (int idx = beg + c; idx < end; idx += 8)
        sum += __int_as_float(emeta[idx].y);
    sum += __shfl_xor(sum, 4, 8);
    sum += __shfl_xor(sum, 2, 8);
    sum += __shfl_xor(sum, 1, 8);
    float di = rsqrtf(2.0f + sum);
    if (c == 0) dinv[node] = di;
    di = __shfl(di, 0, 8);
    size_t off = (size_t)node * 8 + c;
    float4 f = bf16unpack4(H[off]);
    f.x *= di; f.y *= di; f.z *= di; f.w *= di;
    H[off] = bf16pack4(f);
}

// ======== launch ========
extern "C" void kernel_launch(void* const* d_in, const int* in_sizes, int n_in,
                              void* d_out, int out_size, void* d_ws, size_t ws_size,
                              hipStream_t stream) {
    const float* x   = (const float*)d_in[0];
    const int*   ei  = (const int*)d_in[1];
    const float* w   = (const float*)d_in[2];
    const float* W1  = (const float*)d_in[3];
    const float* b1  = (const float*)d_in[4];
    const float* W2  = (const float*)d_in[5];
    const float* b2  = (const float*)d_in[6];
    float*       out = (float*)d_out;

    const int N = in_sizes[0] / D;       // 100000
    const int E = in_sizes[2];           // 1600000
    const int* src = ei;
    const int* dst = ei + E;

    const int NBUCK  = (N + BNODES - 1) / BNODES;    // 782
    const int NBUCKP = (NBUCK + 3) & ~3;             // 784
    const int EPB    = (E + CBLK - 1) / CBLK;        // 3200
    const int NB     = (N + BS - 1) / BS;
    const int E4     = E / 4;
    const int gE4    = (E4 + BS - 1) / BS;
    const int gN8    = (N * 8 + BS - 1) / BS;        // 3125
    const int gN4    = (N * 4 + BS - 1) / BS;        // 1563

    // ---- workspace layout (all segments 16B-aligned) ----
    char*  base    = (char*)d_ws;
    int2*  emeta   = (int2*)base;                                  // E*8
    uint2* ht      = (uint2*)(base + (size_t)E * 8);               // N*8 uint2 (64B/row)
    uint2* ht2     = ht + (size_t)N * 8;                           // N*8 uint2
    float* dinv    = (float*)(ht2 + (size_t)N * 8);                // N*4
    int*   rowptr  = (int*)(dinv + N);                             // (N+4)&~3 ints
    int2*  staged  = (int2*)(rowptr + ((N + 4) & ~3));             // E*8
    int*   bc      = (int*)(staged + E);                           // CBLK*NBUCKP ints
    int*   locoff  = bc + (size_t)CBLK * NBUCKP;                   // CBLK*NBUCKP ints
    int*   bcT     = locoff + (size_t)CBLK * NBUCKP;               // NBUCK*CBLKP ints
    int*   locoffT = bcT + (size_t)NBUCK * CBLKP;                  // NBUCK*CBLKP ints
    int*   btot    = locoffT + (size_t)NBUCK * CBLKP;              // NBUCKP ints
    size_t need    = (size_t)((char*)(btot + NBUCKP) - base);

    bool main_ok = (ws_size >= need) && (NBUCK <= MAXBUCK) && (N < (1 << 17)) &&
                   (EPB <= SBUF_CAP) && (N % 4 == 0);

    if (main_ok) {
        // ---- CSR build: LDS atomics only; coalesced table writes AND reads ----
        hipMemsetAsync(btot, 0, (size_t)NBUCKP * 4, stream);       // graph-capture-safe
        k_localsort_gemm<<<CBLK + gN8, BS, 0, stream>>>(dst, src, w, bc, locoff, staged,
                                                        E, EPB, NBUCK, NBUCKP, x, W1, ht, N);
        dim3 tg((NBUCK + 31) / 32, (CBLK + 31) / 32, 2);
        k_trans<<<tg, BS, 0, stream>>>(bc, locoff, bcT, locoffT, btot, NBUCK, NBUCKP);
        k_merge<<<NBUCK, BS, 0, stream>>>(bcT, locoffT, btot, staged, emeta, rowptr, dinv,
                                          ht, N, E, NBUCK, EPB);
        // ---- layers over pre-scaled tables (4-lane uint4 gathers, em prefetch) ----
        k_agg<true ><<<gN4, BS, 0, stream>>>(rowptr, emeta, (const uint4*)ht,  dinv, b1, W2, ht2, N);
        k_agg<false><<<gN4, BS, 0, stream>>>(rowptr, emeta, (const uint4*)ht2, dinv, b2, nullptr, out, N);
    } else {
        // ---- fallback: global-atomic hist path (same scaled-table semantics) ----
        int* cnt  = (int*)staged;             // N ints (start at POISON_BASE)
        int* rank = cnt + N;                  // E ints
        int* bsum = rank + E;                 // NB ints
        k_hist_gemm<<<gE4 + gN8, BS, 0, stream>>>((const int4*)dst, cnt, (int4*)rank, E4,
                                                  x, W1, ht, N, gE4);
        k_scan1 <<<NB, BS, 0, stream>>>(cnt, bsum, N);
        k_scan23<<<NB, BS, 0, stream>>>(cnt, bsum, rowptr, N);
        k_reorder<<<(E4 + BS - 1) / BS, BS, 0, stream>>>((const int4*)src, (const int4*)dst,
                                                         (const float4*)w, (const int4*)rank,
                                                         rowptr, emeta, E4);
        k_degscaleF<<<gN8, BS, 0, stream>>>(rowptr, emeta, dinv, ht, N);
        k_agg<true ><<<gN4, BS, 0, stream>>>(rowptr, emeta, (const uint4*)ht,  dinv, b1, W2, ht2, N);
        k_agg<false><<<gN4, BS, 0, stream>>>(rowptr, emeta, (const uint4*)ht2, dinv, b2, nullptr, out, N);
    }
}